// Round 3
// baseline (144147.400 us; speedup 1.0000x reference)
//
#include <hip/hip_runtime.h>
#include <stdint.h>

#define B_  16
#define T_  1024
#define H_  1024
#define E_  512
#define V_  256
#define C_  256

typedef __bf16 bf16x8 __attribute__((ext_vector_type(8)));
typedef float  f32x4  __attribute__((ext_vector_type(4)));
typedef unsigned short u16;
typedef unsigned int   u32;

__device__ __forceinline__ float bf2f(u16 u) {
  union { unsigned int i; float f; } v; v.i = ((unsigned int)u) << 16; return v.f;
}
__device__ __forceinline__ u16 f2bf(float f) {
  union { float f; unsigned int i; } v; v.f = f;
  unsigned int u = v.i;
  return (u16)((u + 0x7fffu + ((u >> 16) & 1u)) >> 16);  // RNE
}
__device__ __forceinline__ bf16x8 ld_bf8(const u16* p) {
  uint4 v = *(const uint4*)p;
  return __builtin_bit_cast(bf16x8, v);
}
__device__ __forceinline__ float sigm(float x) { return 1.f / (1.f + __expf(-x)); }

// load 8 weights as bf16x8 from either f32 or bf16 source (flat element offset)
__device__ __forceinline__ bf16x8 ldw8(const void* W, size_t off, bool f32in) {
  if (f32in) {
    const float* p = (const float*)W + off;
    float4 a = *(const float4*)p;
    float4 b = *(const float4*)(p + 4);
    union { u16 s[8]; bf16x8 v; } r;
    r.s[0]=f2bf(a.x); r.s[1]=f2bf(a.y); r.s[2]=f2bf(a.z); r.s[3]=f2bf(a.w);
    r.s[4]=f2bf(b.x); r.s[5]=f2bf(b.y); r.s[6]=f2bf(b.z); r.s[7]=f2bf(b.w);
    return r.v;
  }
  return ld_bf8((const u16*)W + off);
}
__device__ __forceinline__ float ldb1(const void* p, int i, bool f32in) {
  return f32in ? ((const float*)p)[i] : bf2f(((const u16*)p)[i]);
}

// ---- dtype probe: enc_bih0 uniform(-1/32,1/32): bf16 => exponent<=122 always.
__global__ void probe_k(const u16* __restrict__ s, int* __restrict__ flag) {
  if (threadIdx.x == 0) {
    int cnt = 0;
    for (int i = 0; i < 256; ++i) {
      int e = (s[i] >> 7) & 0xFF;
      if (e >= 124) ++cnt;
    }
    flag[0] = (cnt >= 16) ? 1 : 0;
  }
}

__global__ void cvt_k(const void* __restrict__ src, u16* __restrict__ dst, int n,
                      const int* __restrict__ flagp) {
  int i = blockIdx.x * blockDim.x + threadIdx.x;
  if (i >= n) return;
  if (*flagp) dst[i] = f2bf(((const float*)src)[i]);
  else        dst[i] = ((const u16*)src)[i];
}

// ---------------- persistent seq2seq kernel ----------------
struct PersistArgs {
  const int* tok;
  const u16 *eemb, *demb;                 // normalized bf16 (V,512)
  const void *Wih[4], *Whh[4], *bih[4], *bhh[4];  // raw inputs: idx = phase*2+layer
  u16 *zslot;
  u16 *he0[2], *he1[2], *hd0[2], *hd1[2]; // (B,H) ring slots
  u16 *seq;                               // (B,T,H) dec layer1 h
  u32 *flags;                             // 256 flags, 64 B apart
  const int *dflag;
};

struct PhaseP {
  const void *Wx, *Wh, *bi, *bh;
  const u16* emb;
  const int* tok;
  u16 *r0[2], *r1[2];
  const u16 *h0init, *h1init;
  u16* seq;               // non-null only for dec layer1
  u32* flags;
  bool f32in, init_c;
  int c0, bid, tid;
  u32 gp0;
};

__device__ __forceinline__ void gbar(u32* flags, int bid, int tid, u32 gp) {
  __threadfence();
  __syncthreads();
  if (tid == 0)
    __hip_atomic_store(&flags[bid * 16], gp, __ATOMIC_RELEASE, __HIP_MEMORY_SCOPE_AGENT);
  if (tid < 256) {
    while (__hip_atomic_load(&flags[tid * 16], __ATOMIC_ACQUIRE, __HIP_MEMORY_SCOPE_AGENT) < gp)
      __builtin_amdgcn_s_sleep(1);
    __threadfence();
  }
  __syncthreads();
}

// LAYER=0: K_x=512 (emb gather); LAYER=1: K_x=1024 (h0 of this phase).
template<int LAYER>
__device__ u32 run_phase(const PhaseP& q, f32x4* red4, float* gbuf, float* cbuf, float* bbuf) {
  constexpr int KX = LAYER ? 1024 : 512;
  constexpr int NX = KX / 256;            // frags per wave in x-segment
  const int tid = q.tid, w = tid >> 6, l = tid & 63;
  const int rr = l & 15, ksub = (l >> 4) * 8;

  // ---- stage weights into registers (held for the whole phase) ----
  bf16x8 BX[2][NX], BH[2][4];
  #pragma unroll
  for (int t = 0; t < 2; ++t) {
    const size_t row = (size_t)((t * 2 + (rr >> 3)) * 1024 + q.c0 + (rr & 7));
    #pragma unroll
    for (int it = 0; it < NX; ++it)
      BX[t][it] = ldw8(q.Wx, row * KX + w * (KX / 8) + it * 32 + ksub, q.f32in);
    #pragma unroll
    for (int it = 0; it < 4; ++it)
      BH[t][it] = ldw8(q.Wh, row * 1024 + w * 128 + it * 32 + ksub, q.f32in);
  }
  if (tid < 32) {
    const int row = (tid >> 3) * 1024 + q.c0 + (tid & 7);
    bbuf[tid] = ldb1(q.bi, row, q.f32in) + ldb1(q.bh, row, q.f32in);
  }
  if (q.init_c && tid < 128) cbuf[tid] = 0.f;
  __syncthreads();

  int tok_cur = (LAYER == 0) ? q.tok[rr * T_ + 0] : 0;
  u32 gp = q.gp0;

  for (int s = 0; s <= T_; ++s) {
    const bool active = (LAYER == 0) ? (s < T_) : (s >= 1);
    if (active) {
      const u16* xrow;
      const u16* hrow;
      if (LAYER == 0) {
        xrow = q.emb + (size_t)tok_cur * 512;
        hrow = (s == 0) ? (q.h0init + rr * H_) : (q.r0[(s - 1) & 1] + rr * H_);
      } else {
        xrow = q.r0[(s - 1) & 1] + rr * H_;
        hrow = (s == 1) ? (q.h1init + rr * H_) : (q.r1[s & 1] + rr * H_);
      }
      f32x4 a0 = {0.f,0.f,0.f,0.f}, a1 = {0.f,0.f,0.f,0.f};
      #pragma unroll
      for (int it = 0; it < NX; ++it) {
        bf16x8 a = ld_bf8(xrow + w * (KX / 8) + it * 32 + ksub);
        a0 = __builtin_amdgcn_mfma_f32_16x16x32_bf16(a, BX[0][it], a0, 0, 0, 0);
        a1 = __builtin_amdgcn_mfma_f32_16x16x32_bf16(a, BX[1][it], a1, 0, 0, 0);
      }
      #pragma unroll
      for (int it = 0; it < 4; ++it) {
        bf16x8 a = ld_bf8(hrow + w * 128 + it * 32 + ksub);
        a0 = __builtin_amdgcn_mfma_f32_16x16x32_bf16(a, BH[0][it], a0, 0, 0, 0);
        a1 = __builtin_amdgcn_mfma_f32_16x16x32_bf16(a, BH[1][it], a1, 0, 0, 0);
      }
      red4[(w * 2 + 0) * 64 + l] = a0;
      red4[(w * 2 + 1) * 64 + l] = a1;
    }
    if (LAYER == 0) {  // prefetch next step's tokens (pure input)
      const int tn = (s + 1 < T_) ? (s + 1) : (T_ - 1);
      tok_cur = q.tok[rr * T_ + tn];
    }
    __syncthreads();
    if (active && tid < 128) {           // K-split reduction + bias
      const int tt = tid >> 6, ll = tid & 63;
      f32x4 ssum = {0.f,0.f,0.f,0.f};
      #pragma unroll
      for (int w8 = 0; w8 < 8; ++w8) ssum += red4[(w8 * 2 + tt) * 64 + ll];
      const int n = ll & 15, gate = tt * 2 + (n >> 3), j = n & 7, mg = (ll >> 4) * 4;
      const float bsum = bbuf[gate * 8 + j];
      #pragma unroll
      for (int r = 0; r < 4; ++r) gbuf[(gate * 8 + j) * 17 + mg + r] = ssum[r] + bsum;
    }
    __syncthreads();
    if (active && tid < 128) {           // LSTM pointwise (gate order i,f,g,o)
      const int j = tid >> 4, m = tid & 15;
      const int t = (LAYER == 0) ? s : s - 1;
      const float iv = sigm(gbuf[(0  + j) * 17 + m]);
      const float fv = sigm(gbuf[(8  + j) * 17 + m]);
      const float gv = tanhf(gbuf[(16 + j) * 17 + m]);
      const float ov = sigm(gbuf[(24 + j) * 17 + m]);
      const float cn = fv * cbuf[j * 16 + m] + iv * gv;
      cbuf[j * 16 + m] = cn;
      const u16 hv = f2bf(ov * tanhf(cn));
      u16* outs = (LAYER == 0) ? q.r0[s & 1] : q.r1[(s - 1) & 1];
      outs[m * H_ + q.c0 + j] = hv;
      if (q.seq) q.seq[((size_t)m * T_ + t) * H_ + q.c0 + j] = hv;
    }
    gbar(q.flags, q.bid, tid, gp);
    ++gp;
  }
  return gp;
}

__global__ __launch_bounds__(512, 2) void persist_k(PersistArgs P) {
  __shared__ f32x4 red4[16 * 64];   // 16 KB
  __shared__ float gbuf[544];
  __shared__ float cbuf[128];
  __shared__ float bbuf[32];
  const int bid = blockIdx.x, tid = threadIdx.x;
  const int layer = bid >> 7;
  const int c0 = (bid & 127) * 8;
  const bool f32in = (*P.dflag != 0);

  u32 gp = 1;
  for (int ph = 0; ph < 2; ++ph) {
    PhaseP q;
    const int wi = ph * 2 + layer;
    q.Wx = P.Wih[wi]; q.Wh = P.Whh[wi]; q.bi = P.bih[wi]; q.bh = P.bhh[wi];
    q.emb = ph ? P.demb : P.eemb;
    q.tok = P.tok;
    q.r0[0] = ph ? P.hd0[0] : P.he0[0]; q.r0[1] = ph ? P.hd0[1] : P.he0[1];
    q.r1[0] = ph ? P.hd1[0] : P.he1[0]; q.r1[1] = ph ? P.hd1[1] : P.he1[1];
    q.h0init = ph ? P.he0[1] : P.zslot;   // enc t=1023 parity 1
    q.h1init = ph ? P.he1[1] : P.zslot;
    q.seq = (ph == 1 && layer == 1) ? P.seq : nullptr;
    q.flags = P.flags;
    q.f32in = f32in; q.init_c = (ph == 0);
    q.c0 = c0; q.bid = bid; q.tid = tid; q.gp0 = gp;
    gp = layer ? run_phase<1>(q, red4, gbuf, cbuf, bbuf)
               : run_phase<0>(q, red4, gbuf, cbuf, bbuf);
  }
}

// logits[b,c,t] = seq[b,t,:] . outW[c,:] + outb[c]; one wave per 16x16 tile.
__global__ __launch_bounds__(256) void logits_k(const u16* __restrict__ A,
                                                const u16* __restrict__ W,
                                                const u16* __restrict__ bias,
                                                void* __restrict__ out,
                                                const int* __restrict__ dflag) {
  const int wid  = blockIdx.x * 4 + (threadIdx.x >> 6);
  const int mt   = wid >> 4;
  const int nt   = wid & 15;
  const int lane = threadIdx.x & 63;
  const int l15  = lane & 15;
  const int quad = lane >> 4;
  const int ko   = quad * 8;
  const u16* arow = A + (size_t)(mt * 16 + l15) * H_;
  const u16* brow = W + (size_t)(nt * 16 + l15) * H_;
  f32x4 acc = {0.f,0.f,0.f,0.f};
  #pragma unroll 4
  for (int kk = 0; kk < H_; kk += 32) {
    acc = __builtin_amdgcn_mfma_f32_16x16x32_bf16(ld_bf8(arow + kk + ko),
                                                  ld_bf8(brow + kk + ko), acc, 0, 0, 0);
  }
  const int c  = nt * 16 + l15;
  const float bv = bf2f(bias[c]);
  const int f32out = *dflag;
  #pragma unroll
  for (int r = 0; r < 4; ++r) {
    const int m = mt * 16 + quad * 4 + r;
    const int b = m >> 10, t = m & 1023;
    const size_t idx = ((size_t)b * C_ + c) * T_ + t;
    const float v = acc[r] + bv;
    if (f32out) ((float*)out)[idx] = v;
    else        ((u16*)out)[idx]   = f2bf(v);
  }
}

extern "C" void kernel_launch(void* const* d_in, const int* in_sizes, int n_in,
                              void* d_out, int out_size, void* d_ws, size_t ws_size,
                              hipStream_t stream) {
  (void)in_sizes; (void)n_in; (void)out_size; (void)ws_size;

  const int* x = (const int*)d_in[0];

  // ---- workspace layout (~34.9 MiB) ----
  char* ws = (char*)d_ws;
  u32* flags  = (u32*)ws;                       // 16 KiB (256 flags, 64 B apart)
  u16* zslot  = (u16*)(ws + 16384);             // 32 KiB
  int* dflag  = (int*)(ws + 49152);             // 256 B
  char* base  = ws + 49408;
  size_t ob = 0;
  u16* p_eemb = (u16*)(base + ob); ob += (size_t)V_ * E_ * 2;
  u16* p_demb = (u16*)(base + ob); ob += (size_t)V_ * E_ * 2;
  u16* p_outW = (u16*)(base + ob); ob += (size_t)C_ * H_ * 2;
  u16* p_outb = (u16*)(base + ob); ob += 512;
  u16* rings  = (u16*)(base + ob); ob += 8 * (size_t)B_ * H_ * 2;
  u16* seq    = (u16*)(base + ob); ob += (size_t)B_ * T_ * H_ * 2;
  const size_t SLOT = (size_t)B_ * H_;

  // zero flags + zslot (+dflag; probe overwrites it next)
  hipMemsetAsync(ws, 0, 49408, stream);

  // dtype probe on enc_bih0 (d_in[5])
  probe_k<<<1, 64, 0, stream>>>((const u16*)d_in[5], dflag);

  // normalize embeddings + output head to bf16
  cvt_k<<<(V_ * E_ + 255) / 256, 256, 0, stream>>>(d_in[1], p_eemb, V_ * E_, dflag);
  cvt_k<<<(V_ * E_ + 255) / 256, 256, 0, stream>>>(d_in[2], p_demb, V_ * E_, dflag);
  cvt_k<<<(C_ * H_ + 255) / 256, 256, 0, stream>>>(d_in[19], p_outW, C_ * H_, dflag);
  cvt_k<<<1, 256, 0, stream>>>(d_in[20], p_outb, C_, dflag);

  PersistArgs P;
  P.tok = x; P.eemb = p_eemb; P.demb = p_demb;
  for (int l = 0; l < 4; ++l) {   // input order: enc0, enc1, dec0, dec1
    P.Wih[l] = d_in[3 + 4 * l + 0];
    P.Whh[l] = d_in[3 + 4 * l + 1];
    P.bih[l] = d_in[3 + 4 * l + 2];
    P.bhh[l] = d_in[3 + 4 * l + 3];
  }
  P.zslot = zslot;
  P.he0[0] = rings + 0 * SLOT; P.he0[1] = rings + 1 * SLOT;
  P.he1[0] = rings + 2 * SLOT; P.he1[1] = rings + 3 * SLOT;
  P.hd0[0] = rings + 4 * SLOT; P.hd0[1] = rings + 5 * SLOT;
  P.hd1[0] = rings + 6 * SLOT; P.hd1[1] = rings + 7 * SLOT;
  P.seq = seq; P.flags = flags; P.dflag = dflag;

  persist_k<<<256, 512, 0, stream>>>(P);

  logits_k<<<4096, 256, 0, stream>>>(seq, p_outW, p_outb, d_out, dflag);
}

// Round 4
// 16418.346 us; speedup vs baseline: 8.7797x; 8.7797x over previous
//
#include <hip/hip_runtime.h>
#include <stdint.h>

#define B_  16
#define T_  1024
#define H_  1024
#define E_  512
#define V_  256
#define C_  256

typedef __bf16 bf16x8 __attribute__((ext_vector_type(8)));
typedef float  f32x4  __attribute__((ext_vector_type(4)));
typedef unsigned short u16;
typedef unsigned int   u32;
typedef unsigned long long u64;

__device__ __forceinline__ float bf2f(u16 u) {
  union { unsigned int i; float f; } v; v.i = ((unsigned int)u) << 16; return v.f;
}
__device__ __forceinline__ u16 f2bf(float f) {
  union { float f; unsigned int i; } v; v.f = f;
  unsigned int u = v.i;
  return (u16)((u + 0x7fffu + ((u >> 16) & 1u)) >> 16);  // RNE
}
__device__ __forceinline__ bf16x8 ld_bf8(const u16* p) {
  uint4 v = *(const uint4*)p;
  return __builtin_bit_cast(bf16x8, v);
}
__device__ __forceinline__ float sigm(float x) { return 1.f / (1.f + __expf(-x)); }

// load 8 weights as bf16x8 from either f32 or bf16 source (flat element offset)
__device__ __forceinline__ bf16x8 ldw8(const void* W, size_t off, bool f32in) {
  if (f32in) {
    const float* p = (const float*)W + off;
    float4 a = *(const float4*)p;
    float4 b = *(const float4*)(p + 4);
    union { u16 s[8]; bf16x8 v; } r;
    r.s[0]=f2bf(a.x); r.s[1]=f2bf(a.y); r.s[2]=f2bf(a.z); r.s[3]=f2bf(a.w);
    r.s[4]=f2bf(b.x); r.s[5]=f2bf(b.y); r.s[6]=f2bf(b.z); r.s[7]=f2bf(b.w);
    return r.v;
  }
  return ld_bf8((const u16*)W + off);
}
__device__ __forceinline__ float ldb1(const void* p, int i, bool f32in) {
  return f32in ? ((const float*)p)[i] : bf2f(((const u16*)p)[i]);
}

// ---- dtype probe: enc_bih0 uniform(-1/32,1/32): bf16 => exponent<=122 always.
__global__ void probe_k(const u16* __restrict__ s, int* __restrict__ flag) {
  if (threadIdx.x == 0) {
    int cnt = 0;
    for (int i = 0; i < 256; ++i) {
      int e = (s[i] >> 7) & 0xFF;
      if (e >= 124) ++cnt;
    }
    flag[0] = (cnt >= 16) ? 1 : 0;
  }
}

__global__ void cvt_k(const void* __restrict__ src, u16* __restrict__ dst, int n,
                      const int* __restrict__ flagp) {
  int i = blockIdx.x * blockDim.x + threadIdx.x;
  if (i >= n) return;
  if (*flagp) dst[i] = f2bf(((const float*)src)[i]);
  else        dst[i] = ((const u16*)src)[i];
}

// ---------------- persistent seq2seq kernel ----------------
struct PersistArgs {
  const int* tok;
  const u16 *eemb, *demb;                 // normalized bf16 (V,512)
  const void *Wih[4], *Whh[4], *bih[4], *bhh[4];  // raw inputs: idx = phase*2+layer
  u16 *zslot;
  u16 *he0[2], *he1[2], *hd0[2], *hd1[2]; // (B,H) ring slots
  u16 *seq;                               // (B,T,H) dec layer1 h
  u32 *flags;                             // 256 flags, 4 B apart (16 lines)
  const int *dflag;
};

struct PhaseP {
  const void *Wx, *Wh, *bi, *bh;
  const u16* emb;
  const int* tok;
  u16 *r0[2], *r1[2];
  const u16 *h0init, *h1init;
  u16* seq;               // non-null only for dec layer1
  u32* flags;
  bool f32in, init_c;
  int c0, bid, tid;
  u32 gp0;
};

// Cheap grid barrier: relaxed write-through flag store (h-data is already
// globally visible via agent-scope atomic stores drained by __syncthreads),
// RELAXED polling (sc1 loads, no cache maintenance), ONE acquire (buffer_inv)
// per block to discard stale L1/L2 lines before the next step's reads.
__device__ __forceinline__ void gbar(u32* flags, int bid, int tid, u32 gp) {
  __syncthreads();   // drains vmcnt for every wave -> h stores visible device-wide
  if (tid == 0)
    __hip_atomic_store(&flags[bid], gp, __ATOMIC_RELAXED, __HIP_MEMORY_SCOPE_AGENT);
  if (tid < 256) {
    while (__hip_atomic_load(&flags[tid], __ATOMIC_RELAXED, __HIP_MEMORY_SCOPE_AGENT) < gp)
      __builtin_amdgcn_s_sleep(2);
  }
  if (tid == 0)
    (void)__hip_atomic_load(&flags[0], __ATOMIC_ACQUIRE, __HIP_MEMORY_SCOPE_AGENT);
  __syncthreads();
}

// LAYER=0: K_x=512 (emb gather); LAYER=1: K_x=1024 (h0 of this phase).
template<int LAYER>
__device__ u32 run_phase(const PhaseP& q, f32x4* red4, float* gbuf, float* cbuf,
                         float* bbuf, u16* hstage) {
  constexpr int KX = LAYER ? 1024 : 512;
  constexpr int NX = KX / 256;            // frags per wave in x-segment
  const int tid = q.tid, w = tid >> 6, l = tid & 63;
  const int rr = l & 15, ksub = (l >> 4) * 8;

  // ---- stage weights into registers (held for the whole phase) ----
  bf16x8 BX[2][NX], BH[2][4];
  #pragma unroll
  for (int t = 0; t < 2; ++t) {
    const size_t row = (size_t)((t * 2 + (rr >> 3)) * 1024 + q.c0 + (rr & 7));
    #pragma unroll
    for (int it = 0; it < NX; ++it)
      BX[t][it] = ldw8(q.Wx, row * KX + w * (KX / 8) + it * 32 + ksub, q.f32in);
    #pragma unroll
    for (int it = 0; it < 4; ++it)
      BH[t][it] = ldw8(q.Wh, row * 1024 + w * 128 + it * 32 + ksub, q.f32in);
  }
  if (tid < 32) {
    const int row = (tid >> 3) * 1024 + q.c0 + (tid & 7);
    bbuf[tid] = ldb1(q.bi, row, q.f32in) + ldb1(q.bh, row, q.f32in);
  }
  if (q.init_c && tid < 128) cbuf[tid] = 0.f;
  __syncthreads();

  int tok_cur = (LAYER == 0) ? q.tok[rr * T_ + 0] : 0;
  u32 gp = q.gp0;

  for (int s = 0; s <= T_; ++s) {
    const bool active = (LAYER == 0) ? (s < T_) : (s >= 1);
    if (active) {
      const u16* xrow;
      const u16* hrow;
      if (LAYER == 0) {
        xrow = q.emb + (size_t)tok_cur * 512;
        hrow = (s == 0) ? (q.h0init + rr * H_) : (q.r0[(s - 1) & 1] + rr * H_);
      } else {
        xrow = q.r0[(s - 1) & 1] + rr * H_;
        hrow = (s == 1) ? (q.h1init + rr * H_) : (q.r1[s & 1] + rr * H_);
      }
      f32x4 a0 = {0.f,0.f,0.f,0.f}, a1 = {0.f,0.f,0.f,0.f};
      #pragma unroll
      for (int it = 0; it < NX; ++it) {
        bf16x8 a = ld_bf8(xrow + w * (KX / 8) + it * 32 + ksub);
        a0 = __builtin_amdgcn_mfma_f32_16x16x32_bf16(a, BX[0][it], a0, 0, 0, 0);
        a1 = __builtin_amdgcn_mfma_f32_16x16x32_bf16(a, BX[1][it], a1, 0, 0, 0);
      }
      #pragma unroll
      for (int it = 0; it < 4; ++it) {
        bf16x8 a = ld_bf8(hrow + w * 128 + it * 32 + ksub);
        a0 = __builtin_amdgcn_mfma_f32_16x16x32_bf16(a, BH[0][it], a0, 0, 0, 0);
        a1 = __builtin_amdgcn_mfma_f32_16x16x32_bf16(a, BH[1][it], a1, 0, 0, 0);
      }
      red4[(w * 2 + 0) * 64 + l] = a0;
      red4[(w * 2 + 1) * 64 + l] = a1;
    }
    if (LAYER == 0) {  // prefetch next step's tokens (pure input)
      const int tn = (s + 1 < T_) ? (s + 1) : (T_ - 1);
      tok_cur = q.tok[rr * T_ + tn];
    }
    __syncthreads();
    if (active && tid < 128) {           // K-split reduction + bias
      const int tt = tid >> 6, ll = tid & 63;
      f32x4 ssum = {0.f,0.f,0.f,0.f};
      #pragma unroll
      for (int w8 = 0; w8 < 8; ++w8) ssum += red4[(w8 * 2 + tt) * 64 + ll];
      const int n = ll & 15, gate = tt * 2 + (n >> 3), j = n & 7, mg = (ll >> 4) * 4;
      const float bsum = bbuf[gate * 8 + j];
      #pragma unroll
      for (int r = 0; r < 4; ++r) gbuf[(gate * 8 + j) * 17 + mg + r] = ssum[r] + bsum;
    }
    __syncthreads();
    if (active && tid < 128) {           // LSTM pointwise (gate order i,f,g,o)
      const int j = tid >> 4, m = tid & 15;
      const float iv = sigm(gbuf[(0  + j) * 17 + m]);
      const float fv = sigm(gbuf[(8  + j) * 17 + m]);
      const float gv = tanhf(gbuf[(16 + j) * 17 + m]);
      const float ov = sigm(gbuf[(24 + j) * 17 + m]);
      const float cn = fv * cbuf[j * 16 + m] + iv * gv;
      cbuf[j * 16 + m] = cn;
      hstage[m * 8 + j] = f2bf(ov * tanhf(cn));   // stage in LDS
    }
    __syncthreads();
    if (active && tid < 32) {            // write-through h (device-coherent u64)
      const int m = tid >> 1, half = tid & 1;
      const u64 v = ((const u64*)hstage)[m * 2 + half];
      u16* outs = (LAYER == 0) ? q.r0[s & 1] : q.r1[(s - 1) & 1];
      __hip_atomic_store((u64*)(outs + m * H_ + q.c0 + half * 4), v,
                         __ATOMIC_RELAXED, __HIP_MEMORY_SCOPE_AGENT);
      if (q.seq) {
        const int t = s - 1;             // only dec layer1 has q.seq
        __hip_atomic_store((u64*)(q.seq + ((size_t)m * T_ + t) * H_ + q.c0 + half * 4),
                           v, __ATOMIC_RELAXED, __HIP_MEMORY_SCOPE_AGENT);
      }
    }
    gbar(q.flags, q.bid, tid, gp);
    ++gp;
  }
  return gp;
}

__global__ __launch_bounds__(512, 2) void persist_k(PersistArgs P) {
  __shared__ f32x4 red4[16 * 64];   // 16 KB
  __shared__ float gbuf[544];
  __shared__ float cbuf[128];
  __shared__ float bbuf[32];
  __shared__ u16   hstage[128];
  const int bid = blockIdx.x, tid = threadIdx.x;
  const int layer = bid >> 7;
  const int c0 = (bid & 127) * 8;
  const bool f32in = (*P.dflag != 0);

  u32 gp = 1;
  for (int ph = 0; ph < 2; ++ph) {
    PhaseP q;
    const int wi = ph * 2 + layer;
    q.Wx = P.Wih[wi]; q.Wh = P.Whh[wi]; q.bi = P.bih[wi]; q.bh = P.bhh[wi];
    q.emb = ph ? P.demb : P.eemb;
    q.tok = P.tok;
    q.r0[0] = ph ? P.hd0[0] : P.he0[0]; q.r0[1] = ph ? P.hd0[1] : P.he0[1];
    q.r1[0] = ph ? P.hd1[0] : P.he1[0]; q.r1[1] = ph ? P.hd1[1] : P.he1[1];
    q.h0init = ph ? P.he0[1] : P.zslot;   // enc t=1023 parity 1
    q.h1init = ph ? P.he1[1] : P.zslot;
    q.seq = (ph == 1 && layer == 1) ? P.seq : nullptr;
    q.flags = P.flags;
    q.f32in = f32in; q.init_c = (ph == 0);
    q.c0 = c0; q.bid = bid; q.tid = tid; q.gp0 = gp;
    gp = layer ? run_phase<1>(q, red4, gbuf, cbuf, bbuf, hstage)
               : run_phase<0>(q, red4, gbuf, cbuf, bbuf, hstage);
  }
}

// logits[b,c,t] = seq[b,t,:] . outW[c,:] + outb[c]; one wave per 16x16 tile.
__global__ __launch_bounds__(256) void logits_k(const u16* __restrict__ A,
                                                const u16* __restrict__ W,
                                                const u16* __restrict__ bias,
                                                void* __restrict__ out,
                                                const int* __restrict__ dflag) {
  const int wid  = blockIdx.x * 4 + (threadIdx.x >> 6);
  const int mt   = wid >> 4;
  const int nt   = wid & 15;
  const int lane = threadIdx.x & 63;
  const int l15  = lane & 15;
  const int quad = lane >> 4;
  const int ko   = quad * 8;
  const u16* arow = A + (size_t)(mt * 16 + l15) * H_;
  const u16* brow = W + (size_t)(nt * 16 + l15) * H_;
  f32x4 acc = {0.f,0.f,0.f,0.f};
  #pragma unroll 4
  for (int kk = 0; kk < H_; kk += 32) {
    acc = __builtin_amdgcn_mfma_f32_16x16x32_bf16(ld_bf8(arow + kk + ko),
                                                  ld_bf8(brow + kk + ko), acc, 0, 0, 0);
  }
  const int c  = nt * 16 + l15;
  const float bv = bf2f(bias[c]);
  const int f32out = *dflag;
  #pragma unroll
  for (int r = 0; r < 4; ++r) {
    const int m = mt * 16 + quad * 4 + r;
    const int b = m >> 10, t = m & 1023;
    const size_t idx = ((size_t)b * C_ + c) * T_ + t;
    const float v = acc[r] + bv;
    if (f32out) ((float*)out)[idx] = v;
    else        ((u16*)out)[idx]   = f2bf(v);
  }
}

extern "C" void kernel_launch(void* const* d_in, const int* in_sizes, int n_in,
                              void* d_out, int out_size, void* d_ws, size_t ws_size,
                              hipStream_t stream) {
  (void)in_sizes; (void)n_in; (void)out_size; (void)ws_size;

  const int* x = (const int*)d_in[0];

  // ---- workspace layout (~34.9 MiB) ----
  char* ws = (char*)d_ws;
  u32* flags  = (u32*)ws;                       // 1 KiB used (256 x u32)
  u16* zslot  = (u16*)(ws + 16384);             // 32 KiB
  int* dflag  = (int*)(ws + 49152);             // 256 B
  char* base  = ws + 49408;
  size_t ob = 0;
  u16* p_eemb = (u16*)(base + ob); ob += (size_t)V_ * E_ * 2;
  u16* p_demb = (u16*)(base + ob); ob += (size_t)V_ * E_ * 2;
  u16* p_outW = (u16*)(base + ob); ob += (size_t)C_ * H_ * 2;
  u16* p_outb = (u16*)(base + ob); ob += 512;
  u16* rings  = (u16*)(base + ob); ob += 8 * (size_t)B_ * H_ * 2;
  u16* seq    = (u16*)(base + ob); ob += (size_t)B_ * T_ * H_ * 2;
  const size_t SLOT = (size_t)B_ * H_;

  // zero flags + zslot (+dflag; probe overwrites it next)
  hipMemsetAsync(ws, 0, 49408, stream);

  // dtype probe on enc_bih0 (d_in[5])
  probe_k<<<1, 64, 0, stream>>>((const u16*)d_in[5], dflag);

  // normalize embeddings + output head to bf16
  cvt_k<<<(V_ * E_ + 255) / 256, 256, 0, stream>>>(d_in[1], p_eemb, V_ * E_, dflag);
  cvt_k<<<(V_ * E_ + 255) / 256, 256, 0, stream>>>(d_in[2], p_demb, V_ * E_, dflag);
  cvt_k<<<(C_ * H_ + 255) / 256, 256, 0, stream>>>(d_in[19], p_outW, C_ * H_, dflag);
  cvt_k<<<1, 256, 0, stream>>>(d_in[20], p_outb, C_, dflag);

  PersistArgs P;
  P.tok = x; P.eemb = p_eemb; P.demb = p_demb;
  for (int l = 0; l < 4; ++l) {   // input order: enc0, enc1, dec0, dec1
    P.Wih[l] = d_in[3 + 4 * l + 0];
    P.Whh[l] = d_in[3 + 4 * l + 1];
    P.bih[l] = d_in[3 + 4 * l + 2];
    P.bhh[l] = d_in[3 + 4 * l + 3];
  }
  P.zslot = zslot;
  P.he0[0] = rings + 0 * SLOT; P.he0[1] = rings + 1 * SLOT;
  P.he1[0] = rings + 2 * SLOT; P.he1[1] = rings + 3 * SLOT;
  P.hd0[0] = rings + 4 * SLOT; P.hd0[1] = rings + 5 * SLOT;
  P.hd1[0] = rings + 6 * SLOT; P.hd1[1] = rings + 7 * SLOT;
  P.seq = seq; P.flags = flags; P.dflag = dflag;

  persist_k<<<256, 512, 0, stream>>>(P);

  logits_k<<<4096, 256, 0, stream>>>(seq, p_outW, p_outb, d_out, dflag);
}

// Round 5
// 15601.659 us; speedup vs baseline: 9.2392x; 1.0523x over previous
//
#include <hip/hip_runtime.h>
#include <stdint.h>

#define B_  16
#define T_  1024
#define H_  1024
#define E_  512
#define V_  256
#define C_  256

typedef __bf16 bf16x8 __attribute__((ext_vector_type(8)));
typedef float  f32x4  __attribute__((ext_vector_type(4)));
typedef unsigned short u16;
typedef unsigned int   u32;
typedef unsigned long long u64;

__device__ __forceinline__ float bf2f(u16 u) {
  union { unsigned int i; float f; } v; v.i = ((unsigned int)u) << 16; return v.f;
}
__device__ __forceinline__ u16 f2bf(float f) {
  union { float f; unsigned int i; } v; v.f = f;
  unsigned int u = v.i;
  return (u16)((u + 0x7fffu + ((u >> 16) & 1u)) >> 16);  // RNE
}
__device__ __forceinline__ bf16x8 ld_bf8(const u16* p) {
  uint4 v = *(const uint4*)p;
  return __builtin_bit_cast(bf16x8, v);
}
__device__ __forceinline__ float sigm(float x) { return 1.f / (1.f + __expf(-x)); }

// load 8 weights as bf16x8 from either f32 or bf16 source (flat element offset)
__device__ __forceinline__ bf16x8 ldw8(const void* W, size_t off, bool f32in) {
  if (f32in) {
    const float* p = (const float*)W + off;
    float4 a = *(const float4*)p;
    float4 b = *(const float4*)(p + 4);
    union { u16 s[8]; bf16x8 v; } r;
    r.s[0]=f2bf(a.x); r.s[1]=f2bf(a.y); r.s[2]=f2bf(a.z); r.s[3]=f2bf(a.w);
    r.s[4]=f2bf(b.x); r.s[5]=f2bf(b.y); r.s[6]=f2bf(b.z); r.s[7]=f2bf(b.w);
    return r.v;
  }
  return ld_bf8((const u16*)W + off);
}
__device__ __forceinline__ float ldb1(const void* p, int i, bool f32in) {
  return f32in ? ((const float*)p)[i] : bf2f(((const u16*)p)[i]);
}

// ---- dtype probe: enc_bih0 uniform(-1/32,1/32): bf16 => exponent<=122 always.
__global__ void probe_k(const u16* __restrict__ s, int* __restrict__ flag) {
  if (threadIdx.x == 0) {
    int cnt = 0;
    for (int i = 0; i < 256; ++i) {
      int e = (s[i] >> 7) & 0xFF;
      if (e >= 124) ++cnt;
    }
    flag[0] = (cnt >= 16) ? 1 : 0;
  }
}

__global__ void cvt_k(const void* __restrict__ src, u16* __restrict__ dst, int n,
                      const int* __restrict__ flagp) {
  int i = blockIdx.x * blockDim.x + threadIdx.x;
  if (i >= n) return;
  if (*flagp) dst[i] = f2bf(((const float*)src)[i]);
  else        dst[i] = ((const u16*)src)[i];
}

// ---------------- persistent seq2seq kernel ----------------
struct PersistArgs {
  const int* tok;
  const u16 *eemb, *demb;                 // normalized bf16 (V,512)
  const void *Wih[4], *Whh[4], *bih[4], *bhh[4];  // raw inputs: idx = phase*2+layer
  u16 *zslot;
  u16 *he0[2], *he1[2], *hd0[2], *hd1[2]; // (B,H) ring slots
  u16 *seq;                               // (B,T,H) dec layer1 h
  u32 *flags;                             // 256 arrival flags (contiguous u32)
  u32 *bcast;                             // single broadcast epoch word
  const int *dflag;
};

struct PhaseP {
  const void *Wx, *Wh, *bi, *bh;
  const u16* emb;
  const int* tok;
  u16 *r0[2], *r1[2];
  const u16 *h0init, *h1init;
  u16* seq;               // non-null only for dec layer1
  u32 *flags, *bcast;
  bool f32in, init_c;
  int c0, bid, tid;
  u32 gp0;
};

// Two-level grid barrier: arrivals fan in to flags[], ONLY block 0 scans them,
// then publishes a single bcast word that everyone else polls (1 line, 1 load
// per round). Relaxed sc1 ops for all polling (no cache maintenance); exactly
// one acquire (buffer_inv) per block per step before reading remote h data.
__device__ __forceinline__ void gbar(u32* flags, u32* bcast, int bid, int tid, u32 gp) {
  __syncthreads();   // drains each wave's vmcnt -> h stores acked at coherence point
  if (bid == 0) {
    if (tid >= 1 && tid < 256) {
      while (__hip_atomic_load(&flags[tid], __ATOMIC_RELAXED, __HIP_MEMORY_SCOPE_AGENT) < gp)
        __builtin_amdgcn_s_sleep(1);
    }
    __syncthreads();
    if (tid == 0) {
      (void)__hip_atomic_load(&flags[0], __ATOMIC_ACQUIRE, __HIP_MEMORY_SCOPE_AGENT); // inv
      __hip_atomic_store(bcast, gp, __ATOMIC_RELAXED, __HIP_MEMORY_SCOPE_AGENT);
    }
    __syncthreads();
  } else {
    if (tid == 0) {
      __hip_atomic_store(&flags[bid], gp, __ATOMIC_RELAXED, __HIP_MEMORY_SCOPE_AGENT);
      while (__hip_atomic_load(bcast, __ATOMIC_RELAXED, __HIP_MEMORY_SCOPE_AGENT) < gp)
        __builtin_amdgcn_s_sleep(1);
      (void)__hip_atomic_load(&flags[0], __ATOMIC_ACQUIRE, __HIP_MEMORY_SCOPE_AGENT); // inv
    }
    __syncthreads();
  }
}

// LAYER=0: K_x=512 (emb gather); LAYER=1: K_x=1024 (h0 of this phase).
template<int LAYER>
__device__ u32 run_phase(const PhaseP& q, f32x4* red4, float* gbuf, float* cbuf,
                         float* bbuf) {
  constexpr int KX = LAYER ? 1024 : 512;
  constexpr int NX = KX / 256;            // frags per wave in x-segment
  const int tid = q.tid, w = tid >> 6, l = tid & 63;
  const int rr = l & 15, ksub = (l >> 4) * 8;

  // ---- stage weights into registers (held for the whole phase) ----
  bf16x8 BX[2][NX], BH[2][4];
  #pragma unroll
  for (int t = 0; t < 2; ++t) {
    const size_t row = (size_t)((t * 2 + (rr >> 3)) * 1024 + q.c0 + (rr & 7));
    #pragma unroll
    for (int it = 0; it < NX; ++it)
      BX[t][it] = ldw8(q.Wx, row * KX + w * (KX / 8) + it * 32 + ksub, q.f32in);
    #pragma unroll
    for (int it = 0; it < 4; ++it)
      BH[t][it] = ldw8(q.Wh, row * 1024 + w * 128 + it * 32 + ksub, q.f32in);
  }
  if (tid < 32) {
    const int row = (tid >> 3) * 1024 + q.c0 + (tid & 7);
    bbuf[tid] = ldb1(q.bi, row, q.f32in) + ldb1(q.bh, row, q.f32in);
  }
  if (q.init_c && tid < 128) cbuf[tid] = 0.f;
  __syncthreads();

  int tok_cur = (LAYER == 0) ? q.tok[rr * T_ + 0] : 0;
  u32 gp = q.gp0;

  for (int s = 0; s <= T_; ++s) {
    const bool active = (LAYER == 0) ? (s < T_) : (s >= 1);
    if (active) {
      const u16* xrow;
      const u16* hrow;
      if (LAYER == 0) {
        xrow = q.emb + (size_t)tok_cur * 512;
        hrow = (s == 0) ? (q.h0init + rr * H_) : (q.r0[(s - 1) & 1] + rr * H_);
      } else {
        xrow = q.r0[(s - 1) & 1] + rr * H_;
        hrow = (s == 1) ? (q.h1init + rr * H_) : (q.r1[s & 1] + rr * H_);
      }
      f32x4 a0 = {0.f,0.f,0.f,0.f}, a1 = {0.f,0.f,0.f,0.f};
      #pragma unroll
      for (int it = 0; it < NX; ++it) {
        bf16x8 a = ld_bf8(xrow + w * (KX / 8) + it * 32 + ksub);
        a0 = __builtin_amdgcn_mfma_f32_16x16x32_bf16(a, BX[0][it], a0, 0, 0, 0);
        a1 = __builtin_amdgcn_mfma_f32_16x16x32_bf16(a, BX[1][it], a1, 0, 0, 0);
      }
      #pragma unroll
      for (int it = 0; it < 4; ++it) {
        bf16x8 a = ld_bf8(hrow + w * 128 + it * 32 + ksub);
        a0 = __builtin_amdgcn_mfma_f32_16x16x32_bf16(a, BH[0][it], a0, 0, 0, 0);
        a1 = __builtin_amdgcn_mfma_f32_16x16x32_bf16(a, BH[1][it], a1, 0, 0, 0);
      }
      red4[(w * 2 + 0) * 64 + l] = a0;
      red4[(w * 2 + 1) * 64 + l] = a1;
    }
    if (LAYER == 0) {  // prefetch next step's tokens (pure input)
      const int tn = (s + 1 < T_) ? (s + 1) : (T_ - 1);
      tok_cur = q.tok[rr * T_ + tn];
    }
    __syncthreads();
    if (active && tid < 128) {           // K-split reduction + bias
      const int tt = tid >> 6, ll = tid & 63;
      f32x4 ssum = {0.f,0.f,0.f,0.f};
      #pragma unroll
      for (int w8 = 0; w8 < 8; ++w8) ssum += red4[(w8 * 2 + tt) * 64 + ll];
      const int n = ll & 15, gate = tt * 2 + (n >> 3), j = n & 7, mg = (ll >> 4) * 4;
      const float bsum = bbuf[gate * 8 + j];
      #pragma unroll
      for (int r = 0; r < 4; ++r) gbuf[(gate * 8 + j) * 17 + mg + r] = ssum[r] + bsum;
    }
    __syncthreads();
    if (active && tid < 128) {           // LSTM pointwise + direct h write-through
      const int j = tid >> 4, m = tid & 15;
      const float iv = sigm(gbuf[(0  + j) * 17 + m]);
      const float fv = sigm(gbuf[(8  + j) * 17 + m]);
      const float gv = tanhf(gbuf[(16 + j) * 17 + m]);
      const float ov = sigm(gbuf[(24 + j) * 17 + m]);
      const float cn = fv * cbuf[j * 16 + m] + iv * gv;
      cbuf[j * 16 + m] = cn;
      const u16 hv = f2bf(ov * tanhf(cn));
      u16* outs = (LAYER == 0) ? q.r0[s & 1] : q.r1[(s - 1) & 1];
      __hip_atomic_store(outs + m * H_ + q.c0 + j, hv,
                         __ATOMIC_RELAXED, __HIP_MEMORY_SCOPE_AGENT);
      if (q.seq) {
        const int t = s - 1;             // only dec layer1 has q.seq
        __hip_atomic_store(q.seq + ((size_t)m * T_ + t) * H_ + q.c0 + j, hv,
                           __ATOMIC_RELAXED, __HIP_MEMORY_SCOPE_AGENT);
      }
    }
    gbar(q.flags, q.bcast, q.bid, tid, gp);
    ++gp;
  }
  return gp;
}

__global__ __launch_bounds__(512, 2) void persist_k(PersistArgs P) {
  __shared__ f32x4 red4[16 * 64];   // 16 KB
  __shared__ float gbuf[544];
  __shared__ float cbuf[128];
  __shared__ float bbuf[32];
  const int bid = blockIdx.x, tid = threadIdx.x;
  const int layer = bid >> 7;
  const int c0 = (bid & 127) * 8;
  const bool f32in = (*P.dflag != 0);

  u32 gp = 1;
  for (int ph = 0; ph < 2; ++ph) {
    PhaseP q;
    const int wi = ph * 2 + layer;
    q.Wx = P.Wih[wi]; q.Wh = P.Whh[wi]; q.bi = P.bih[wi]; q.bh = P.bhh[wi];
    q.emb = ph ? P.demb : P.eemb;
    q.tok = P.tok;
    q.r0[0] = ph ? P.hd0[0] : P.he0[0]; q.r0[1] = ph ? P.hd0[1] : P.he0[1];
    q.r1[0] = ph ? P.hd1[0] : P.he1[0]; q.r1[1] = ph ? P.hd1[1] : P.he1[1];
    q.h0init = ph ? P.he0[1] : P.zslot;   // enc t=1023 parity 1
    q.h1init = ph ? P.he1[1] : P.zslot;
    q.seq = (ph == 1 && layer == 1) ? P.seq : nullptr;
    q.flags = P.flags; q.bcast = P.bcast;
    q.f32in = f32in; q.init_c = (ph == 0);
    q.c0 = c0; q.bid = bid; q.tid = tid; q.gp0 = gp;
    gp = layer ? run_phase<1>(q, red4, gbuf, cbuf, bbuf)
               : run_phase<0>(q, red4, gbuf, cbuf, bbuf);
  }
}

// logits[b,c,t] = seq[b,t,:] . outW[c,:] + outb[c]; one wave per 16x16 tile.
__global__ __launch_bounds__(256) void logits_k(const u16* __restrict__ A,
                                                const u16* __restrict__ W,
                                                const u16* __restrict__ bias,
                                                void* __restrict__ out,
                                                const int* __restrict__ dflag) {
  const int wid  = blockIdx.x * 4 + (threadIdx.x >> 6);
  const int mt   = wid >> 4;
  const int nt   = wid & 15;
  const int lane = threadIdx.x & 63;
  const int l15  = lane & 15;
  const int quad = lane >> 4;
  const int ko   = quad * 8;
  const u16* arow = A + (size_t)(mt * 16 + l15) * H_;
  const u16* brow = W + (size_t)(nt * 16 + l15) * H_;
  f32x4 acc = {0.f,0.f,0.f,0.f};
  #pragma unroll 4
  for (int kk = 0; kk < H_; kk += 32) {
    acc = __builtin_amdgcn_mfma_f32_16x16x32_bf16(ld_bf8(arow + kk + ko),
                                                  ld_bf8(brow + kk + ko), acc, 0, 0, 0);
  }
  const int c  = nt * 16 + l15;
  const float bv = bf2f(bias[c]);
  const int f32out = *dflag;
  #pragma unroll
  for (int r = 0; r < 4; ++r) {
    const int m = mt * 16 + quad * 4 + r;
    const int b = m >> 10, t = m & 1023;
    const size_t idx = ((size_t)b * C_ + c) * T_ + t;
    const float v = acc[r] + bv;
    if (f32out) ((float*)out)[idx] = v;
    else        ((u16*)out)[idx]   = f2bf(v);
  }
}

extern "C" void kernel_launch(void* const* d_in, const int* in_sizes, int n_in,
                              void* d_out, int out_size, void* d_ws, size_t ws_size,
                              hipStream_t stream) {
  (void)in_sizes; (void)n_in; (void)out_size; (void)ws_size;

  const int* x = (const int*)d_in[0];

  // ---- workspace layout (~34.9 MiB) ----
  char* ws = (char*)d_ws;
  u32* flags  = (u32*)ws;                       // 1 KiB used (256 x u32)
  u32* bcast  = (u32*)(ws + 8192);              // broadcast epoch (own line)
  u16* zslot  = (u16*)(ws + 16384);             // 32 KiB
  int* dflag  = (int*)(ws + 49152);             // 256 B
  char* base  = ws + 49408;
  size_t ob = 0;
  u16* p_eemb = (u16*)(base + ob); ob += (size_t)V_ * E_ * 2;
  u16* p_demb = (u16*)(base + ob); ob += (size_t)V_ * E_ * 2;
  u16* p_outW = (u16*)(base + ob); ob += (size_t)C_ * H_ * 2;
  u16* p_outb = (u16*)(base + ob); ob += 512;
  u16* rings  = (u16*)(base + ob); ob += 8 * (size_t)B_ * H_ * 2;
  u16* seq    = (u16*)(base + ob); ob += (size_t)B_ * T_ * H_ * 2;
  const size_t SLOT = (size_t)B_ * H_;

  // zero flags + bcast + zslot (+dflag; probe overwrites it next)
  hipMemsetAsync(ws, 0, 49408, stream);

  // dtype probe on enc_bih0 (d_in[5])
  probe_k<<<1, 64, 0, stream>>>((const u16*)d_in[5], dflag);

  // normalize embeddings + output head to bf16
  cvt_k<<<(V_ * E_ + 255) / 256, 256, 0, stream>>>(d_in[1], p_eemb, V_ * E_, dflag);
  cvt_k<<<(V_ * E_ + 255) / 256, 256, 0, stream>>>(d_in[2], p_demb, V_ * E_, dflag);
  cvt_k<<<(C_ * H_ + 255) / 256, 256, 0, stream>>>(d_in[19], p_outW, C_ * H_, dflag);
  cvt_k<<<1, 256, 0, stream>>>(d_in[20], p_outb, C_, dflag);

  PersistArgs P;
  P.tok = x; P.eemb = p_eemb; P.demb = p_demb;
  for (int l = 0; l < 4; ++l) {   // input order: enc0, enc1, dec0, dec1
    P.Wih[l] = d_in[3 + 4 * l + 0];
    P.Whh[l] = d_in[3 + 4 * l + 1];
    P.bih[l] = d_in[3 + 4 * l + 2];
    P.bhh[l] = d_in[3 + 4 * l + 3];
  }
  P.zslot = zslot;
  P.he0[0] = rings + 0 * SLOT; P.he0[1] = rings + 1 * SLOT;
  P.he1[0] = rings + 2 * SLOT; P.he1[1] = rings + 3 * SLOT;
  P.hd0[0] = rings + 4 * SLOT; P.hd0[1] = rings + 5 * SLOT;
  P.hd1[0] = rings + 6 * SLOT; P.hd1[1] = rings + 7 * SLOT;
  P.seq = seq; P.flags = flags; P.bcast = bcast; P.dflag = dflag;

  persist_k<<<256, 512, 0, stream>>>(P);

  logits_k<<<4096, 256, 0, stream>>>(seq, p_outW, p_outb, d_out, dflag);
}

// Round 6
// 14588.350 us; speedup vs baseline: 9.8810x; 1.0695x over previous
//
#include <hip/hip_runtime.h>
#include <stdint.h>

#define B_  16
#define T_  1024
#define H_  1024
#define E_  512
#define V_  256
#define C_  256

typedef __bf16 bf16x8 __attribute__((ext_vector_type(8)));
typedef float  f32x4  __attribute__((ext_vector_type(4)));
typedef unsigned short u16;
typedef unsigned int   u32;
typedef unsigned long long u64;

__device__ __forceinline__ float bf2f(u16 u) {
  union { unsigned int i; float f; } v; v.i = ((unsigned int)u) << 16; return v.f;
}
__device__ __forceinline__ u16 f2bf(float f) {
  union { float f; unsigned int i; } v; v.f = f;
  unsigned int u = v.i;
  return (u16)((u + 0x7fffu + ((u >> 16) & 1u)) >> 16);  // RNE
}
__device__ __forceinline__ bf16x8 ld_bf8(const u16* p) {
  uint4 v = *(const uint4*)p;
  return __builtin_bit_cast(bf16x8, v);
}
// Coherent (agent-scope, cache-bypassing) 16B load from ring buffers.
__device__ __forceinline__ bf16x8 ld_bf8_coh(const u16* p) {
  union { u64 q[2]; bf16x8 v; } r;
  r.q[0] = __hip_atomic_load((const u64*)p,     __ATOMIC_RELAXED, __HIP_MEMORY_SCOPE_AGENT);
  r.q[1] = __hip_atomic_load((const u64*)p + 1, __ATOMIC_RELAXED, __HIP_MEMORY_SCOPE_AGENT);
  return r.v;
}
__device__ __forceinline__ float sigm(float x) { return 1.f / (1.f + __expf(-x)); }

// load 8 weights as bf16x8 from either f32 or bf16 source (flat element offset)
__device__ __forceinline__ bf16x8 ldw8(const void* W, size_t off, bool f32in) {
  if (f32in) {
    const float* p = (const float*)W + off;
    float4 a = *(const float4*)p;
    float4 b = *(const float4*)(p + 4);
    union { u16 s[8]; bf16x8 v; } r;
    r.s[0]=f2bf(a.x); r.s[1]=f2bf(a.y); r.s[2]=f2bf(a.z); r.s[3]=f2bf(a.w);
    r.s[4]=f2bf(b.x); r.s[5]=f2bf(b.y); r.s[6]=f2bf(b.z); r.s[7]=f2bf(b.w);
    return r.v;
  }
  return ld_bf8((const u16*)W + off);
}
__device__ __forceinline__ float ldb1(const void* p, int i, bool f32in) {
  return f32in ? ((const float*)p)[i] : bf2f(((const u16*)p)[i]);
}

// ---- dtype probe: enc_bih0 uniform(-1/32,1/32): bf16 => exponent<=122 always.
__global__ void probe_k(const u16* __restrict__ s, int* __restrict__ flag) {
  if (threadIdx.x == 0) {
    int cnt = 0;
    for (int i = 0; i < 256; ++i) {
      int e = (s[i] >> 7) & 0xFF;
      if (e >= 124) ++cnt;
    }
    flag[0] = (cnt >= 16) ? 1 : 0;
  }
}

__global__ void cvt_k(const void* __restrict__ src, u16* __restrict__ dst, int n,
                      const int* __restrict__ flagp) {
  int i = blockIdx.x * blockDim.x + threadIdx.x;
  if (i >= n) return;
  if (*flagp) dst[i] = f2bf(((const float*)src)[i]);
  else        dst[i] = ((const u16*)src)[i];
}

// ---------------- persistent seq2seq kernel ----------------
struct PersistArgs {
  const int* tok;
  const u16 *eemb, *demb;                 // normalized bf16 (V,512)
  const void *Wih[4], *Whh[4], *bih[4], *bhh[4];  // raw inputs: idx = phase*2+layer
  u16 *zslot;
  u16 *he0[2], *he1[2], *hd0[2], *hd1[2]; // (B,H) ring slots
  u16 *seq;                               // (B,T,H) dec layer1 h
  u32 *flags;                             // 256 flags, 64 B apart
  const int *dflag;
};

struct PhaseP {
  const void *Wx, *Wh, *bi, *bh;
  const u16* emb;
  const int* tok;
  u16 *r0[2], *r1[2];
  const u16 *h0init, *h1init;
  u16* seq;               // non-null only for dec layer1
  u32 *flags;
  bool f32in, init_c;
  int c0, bid, tid;
  u32 gp0;
};

// Single-hop grid barrier, zero cache maintenance: every mutable datum is
// accessed with agent-scope (sc1) ops, so no inv/wb needed anywhere. Each
// block posts its epoch; 256 threads poll the 256 producer flags directly.
// __syncthreads() drains each wave's vmcnt, so all h stores are acked at the
// coherence point before tid0 publishes the flag.
__device__ __forceinline__ void gbar(u32* flags, int bid, int tid, u32 gp) {
  __syncthreads();
  if (tid == 0)
    __hip_atomic_store(&flags[bid * 16], gp, __ATOMIC_RELAXED, __HIP_MEMORY_SCOPE_AGENT);
  if (tid < 256) {
    while (__hip_atomic_load(&flags[tid * 16], __ATOMIC_RELAXED, __HIP_MEMORY_SCOPE_AGENT) < gp)
      __builtin_amdgcn_s_sleep(2);
  }
  __syncthreads();
}

// LAYER=0: K_x=512 (emb gather); LAYER=1: K_x=1024 (h0 of this phase).
template<int LAYER>
__device__ u32 run_phase(const PhaseP& q, f32x4* red4, float* gbuf, float* cbuf,
                         float* bbuf) {
  constexpr int KX = LAYER ? 1024 : 512;
  constexpr int NX = KX / 256;            // frags per wave in x-segment
  const int tid = q.tid, w = tid >> 6, l = tid & 63;
  const int rr = l & 15, ksub = (l >> 4) * 8;

  // ---- stage weights into registers (held for the whole phase) ----
  bf16x8 BX[2][NX], BH[2][4];
  #pragma unroll
  for (int t = 0; t < 2; ++t) {
    const size_t row = (size_t)((t * 2 + (rr >> 3)) * 1024 + q.c0 + (rr & 7));
    #pragma unroll
    for (int it = 0; it < NX; ++it)
      BX[t][it] = ldw8(q.Wx, row * KX + w * (KX / 8) + it * 32 + ksub, q.f32in);
    #pragma unroll
    for (int it = 0; it < 4; ++it)
      BH[t][it] = ldw8(q.Wh, row * 1024 + w * 128 + it * 32 + ksub, q.f32in);
  }
  if (tid < 32) {
    const int row = (tid >> 3) * 1024 + q.c0 + (tid & 7);
    bbuf[tid] = ldb1(q.bi, row, q.f32in) + ldb1(q.bh, row, q.f32in);
  }
  if (q.init_c && tid < 128) cbuf[tid] = 0.f;
  __syncthreads();

  int tok_cur = (LAYER == 0) ? q.tok[rr * T_ + 0] : 0;
  u32 gp = q.gp0;

  for (int s = 0; s <= T_; ++s) {
    const bool active = (LAYER == 0) ? (s < T_) : (s >= 1);
    if (active) {
      const u16* xrow;
      const u16* hrow;
      if (LAYER == 0) {
        xrow = q.emb + (size_t)tok_cur * 512;
        hrow = (s == 0) ? (q.h0init + rr * H_) : (q.r0[(s - 1) & 1] + rr * H_);
      } else {
        xrow = q.r0[(s - 1) & 1] + rr * H_;
        hrow = (s == 1) ? (q.h1init + rr * H_) : (q.r1[s & 1] + rr * H_);
      }
      f32x4 a0 = {0.f,0.f,0.f,0.f}, a1 = {0.f,0.f,0.f,0.f};
      if (LAYER == 0) {     // emb: static, cached loads
        #pragma unroll
        for (int it = 0; it < NX; ++it) {
          bf16x8 a = ld_bf8(xrow + w * (KX / 8) + it * 32 + ksub);
          a0 = __builtin_amdgcn_mfma_f32_16x16x32_bf16(a, BX[0][it], a0, 0, 0, 0);
          a1 = __builtin_amdgcn_mfma_f32_16x16x32_bf16(a, BX[1][it], a1, 0, 0, 0);
        }
      } else {              // ring: coherent loads
        #pragma unroll
        for (int it = 0; it < NX; ++it) {
          bf16x8 a = ld_bf8_coh(xrow + w * (KX / 8) + it * 32 + ksub);
          a0 = __builtin_amdgcn_mfma_f32_16x16x32_bf16(a, BX[0][it], a0, 0, 0, 0);
          a1 = __builtin_amdgcn_mfma_f32_16x16x32_bf16(a, BX[1][it], a1, 0, 0, 0);
        }
      }
      #pragma unroll
      for (int it = 0; it < 4; ++it) {
        bf16x8 a = ld_bf8_coh(hrow + w * 128 + it * 32 + ksub);
        a0 = __builtin_amdgcn_mfma_f32_16x16x32_bf16(a, BH[0][it], a0, 0, 0, 0);
        a1 = __builtin_amdgcn_mfma_f32_16x16x32_bf16(a, BH[1][it], a1, 0, 0, 0);
      }
      red4[(w * 2 + 0) * 64 + l] = a0;
      red4[(w * 2 + 1) * 64 + l] = a1;
    }
    if (LAYER == 0) {  // prefetch next step's tokens (pure input)
      const int tn = (s + 1 < T_) ? (s + 1) : (T_ - 1);
      tok_cur = q.tok[rr * T_ + tn];
    }
    __syncthreads();
    if (active && tid < 128) {           // K-split reduction + bias
      const int tt = tid >> 6, ll = tid & 63;
      f32x4 ssum = {0.f,0.f,0.f,0.f};
      #pragma unroll
      for (int w8 = 0; w8 < 8; ++w8) ssum += red4[(w8 * 2 + tt) * 64 + ll];
      const int n = ll & 15, gate = tt * 2 + (n >> 3), j = n & 7, mg = (ll >> 4) * 4;
      const float bsum = bbuf[gate * 8 + j];
      #pragma unroll
      for (int r = 0; r < 4; ++r) gbuf[(gate * 8 + j) * 17 + mg + r] = ssum[r] + bsum;
    }
    __syncthreads();
    if (active && tid < 128) {           // LSTM pointwise + direct h write-through
      const int j = tid >> 4, m = tid & 15;
      const float iv = sigm(gbuf[(0  + j) * 17 + m]);
      const float fv = sigm(gbuf[(8  + j) * 17 + m]);
      const float gv = tanhf(gbuf[(16 + j) * 17 + m]);
      const float ov = sigm(gbuf[(24 + j) * 17 + m]);
      const float cn = fv * cbuf[j * 16 + m] + iv * gv;
      cbuf[j * 16 + m] = cn;
      const u16 hv = f2bf(ov * tanhf(cn));
      u16* outs = (LAYER == 0) ? q.r0[s & 1] : q.r1[(s - 1) & 1];
      __hip_atomic_store(outs + m * H_ + q.c0 + j, hv,
                         __ATOMIC_RELAXED, __HIP_MEMORY_SCOPE_AGENT);
      if (q.seq) {
        const int t = s - 1;             // only dec layer1 has q.seq
        __hip_atomic_store(q.seq + ((size_t)m * T_ + t) * H_ + q.c0 + j, hv,
                           __ATOMIC_RELAXED, __HIP_MEMORY_SCOPE_AGENT);
      }
    }
    gbar(q.flags, q.bid, tid, gp);
    ++gp;
  }
  return gp;
}

__global__ __launch_bounds__(512, 2) void persist_k(PersistArgs P) {
  __shared__ f32x4 red4[16 * 64];   // 16 KB
  __shared__ float gbuf[544];
  __shared__ float cbuf[128];
  __shared__ float bbuf[32];
  const int bid = blockIdx.x, tid = threadIdx.x;
  const int layer = bid >> 7;
  const int c0 = (bid & 127) * 8;
  const bool f32in = (*P.dflag != 0);

  u32 gp = 1;
  for (int ph = 0; ph < 2; ++ph) {
    PhaseP q;
    const int wi = ph * 2 + layer;
    q.Wx = P.Wih[wi]; q.Wh = P.Whh[wi]; q.bi = P.bih[wi]; q.bh = P.bhh[wi];
    q.emb = ph ? P.demb : P.eemb;
    q.tok = P.tok;
    q.r0[0] = ph ? P.hd0[0] : P.he0[0]; q.r0[1] = ph ? P.hd0[1] : P.he0[1];
    q.r1[0] = ph ? P.hd1[0] : P.he1[0]; q.r1[1] = ph ? P.hd1[1] : P.he1[1];
    q.h0init = ph ? P.he0[1] : P.zslot;   // enc t=1023 parity 1
    q.h1init = ph ? P.he1[1] : P.zslot;
    q.seq = (ph == 1 && layer == 1) ? P.seq : nullptr;
    q.flags = P.flags;
    q.f32in = f32in; q.init_c = (ph == 0);
    q.c0 = c0; q.bid = bid; q.tid = tid; q.gp0 = gp;
    gp = layer ? run_phase<1>(q, red4, gbuf, cbuf, bbuf)
               : run_phase<0>(q, red4, gbuf, cbuf, bbuf);
  }
}

// logits[b,c,t] = seq[b,t,:] . outW[c,:] + outb[c]; one wave per 16x16 tile.
__global__ __launch_bounds__(256) void logits_k(const u16* __restrict__ A,
                                                const u16* __restrict__ W,
                                                const u16* __restrict__ bias,
                                                void* __restrict__ out,
                                                const int* __restrict__ dflag) {
  const int wid  = blockIdx.x * 4 + (threadIdx.x >> 6);
  const int mt   = wid >> 4;
  const int nt   = wid & 15;
  const int lane = threadIdx.x & 63;
  const int l15  = lane & 15;
  const int quad = lane >> 4;
  const int ko   = quad * 8;
  const u16* arow = A + (size_t)(mt * 16 + l15) * H_;
  const u16* brow = W + (size_t)(nt * 16 + l15) * H_;
  f32x4 acc = {0.f,0.f,0.f,0.f};
  #pragma unroll 4
  for (int kk = 0; kk < H_; kk += 32) {
    acc = __builtin_amdgcn_mfma_f32_16x16x32_bf16(ld_bf8(arow + kk + ko),
                                                  ld_bf8(brow + kk + ko), acc, 0, 0, 0);
  }
  const int c  = nt * 16 + l15;
  const float bv = bf2f(bias[c]);
  const int f32out = *dflag;
  #pragma unroll
  for (int r = 0; r < 4; ++r) {
    const int m = mt * 16 + quad * 4 + r;
    const int b = m >> 10, t = m & 1023;
    const size_t idx = ((size_t)b * C_ + c) * T_ + t;
    const float v = acc[r] + bv;
    if (f32out) ((float*)out)[idx] = v;
    else        ((u16*)out)[idx]   = f2bf(v);
  }
}

extern "C" void kernel_launch(void* const* d_in, const int* in_sizes, int n_in,
                              void* d_out, int out_size, void* d_ws, size_t ws_size,
                              hipStream_t stream) {
  (void)in_sizes; (void)n_in; (void)out_size; (void)ws_size;

  const int* x = (const int*)d_in[0];

  // ---- workspace layout (~34.9 MiB) ----
  char* ws = (char*)d_ws;
  u32* flags  = (u32*)ws;                       // 16 KiB (256 flags, 64 B apart)
  u16* zslot  = (u16*)(ws + 16384);             // 32 KiB
  int* dflag  = (int*)(ws + 49152);             // 256 B
  char* base  = ws + 49408;
  size_t ob = 0;
  u16* p_eemb = (u16*)(base + ob); ob += (size_t)V_ * E_ * 2;
  u16* p_demb = (u16*)(base + ob); ob += (size_t)V_ * E_ * 2;
  u16* p_outW = (u16*)(base + ob); ob += (size_t)C_ * H_ * 2;
  u16* p_outb = (u16*)(base + ob); ob += 512;
  u16* rings  = (u16*)(base + ob); ob += 8 * (size_t)B_ * H_ * 2;
  u16* seq    = (u16*)(base + ob); ob += (size_t)B_ * T_ * H_ * 2;
  const size_t SLOT = (size_t)B_ * H_;

  // zero flags + zslot (+dflag; probe overwrites it next)
  hipMemsetAsync(ws, 0, 49408, stream);

  // dtype probe on enc_bih0 (d_in[5])
  probe_k<<<1, 64, 0, stream>>>((const u16*)d_in[5], dflag);

  // normalize embeddings + output head to bf16
  cvt_k<<<(V_ * E_ + 255) / 256, 256, 0, stream>>>(d_in[1], p_eemb, V_ * E_, dflag);
  cvt_k<<<(V_ * E_ + 255) / 256, 256, 0, stream>>>(d_in[2], p_demb, V_ * E_, dflag);
  cvt_k<<<(C_ * H_ + 255) / 256, 256, 0, stream>>>(d_in[19], p_outW, C_ * H_, dflag);
  cvt_k<<<1, 256, 0, stream>>>(d_in[20], p_outb, C_, dflag);

  PersistArgs P;
  P.tok = x; P.eemb = p_eemb; P.demb = p_demb;
  for (int l = 0; l < 4; ++l) {   // input order: enc0, enc1, dec0, dec1
    P.Wih[l] = d_in[3 + 4 * l + 0];
    P.Whh[l] = d_in[3 + 4 * l + 1];
    P.bih[l] = d_in[3 + 4 * l + 2];
    P.bhh[l] = d_in[3 + 4 * l + 3];
  }
  P.zslot = zslot;
  P.he0[0] = rings + 0 * SLOT; P.he0[1] = rings + 1 * SLOT;
  P.he1[0] = rings + 2 * SLOT; P.he1[1] = rings + 3 * SLOT;
  P.hd0[0] = rings + 4 * SLOT; P.hd0[1] = rings + 5 * SLOT;
  P.hd1[0] = rings + 6 * SLOT; P.hd1[1] = rings + 7 * SLOT;
  P.seq = seq; P.flags = flags; P.dflag = dflag;

  persist_k<<<256, 512, 0, stream>>>(P);

  logits_k<<<4096, 256, 0, stream>>>(seq, p_outW, p_outb, d_out, dflag);
}